// Round 4
// baseline (196.878 us; speedup 1.0000x reference)
//
#include <hip/hip_runtime.h>
#include <hip/hip_bf16.h>

typedef __attribute__((ext_vector_type(8))) short bf16x8;
typedef __attribute__((ext_vector_type(4))) float f32x4;

#define NTOK   2048
#define NEXP   16
#define NF     512
#define NH     1024
#define NCOUT  512
#define NPAIR  8192   // NTOK * 4

__device__ __forceinline__ void gload16_lds(const __hip_bfloat16* g, __hip_bfloat16* l) {
  __builtin_amdgcn_global_load_lds((const __attribute__((address_space(1))) void*)g,
                                   (__attribute__((address_space(3))) void*)l, 16, 0, 0);
}

// ---------------- precompute exp(W_logvar), exp(b_logvar) ----------------
__global__ __launch_bounds__(256) void precompute_kernel(
    const float* __restrict__ W_logvar, const float* __restrict__ b_logvar,
    float* __restrict__ expW, float* __restrict__ expb)
{
  int i = blockIdx.x * 256 + threadIdx.x;
  if (i < NEXP * NF) expW[i] = expf(W_logvar[i]);
  if (i < NEXP) expb[i] = expf(b_logvar[i]);
}

// ---------------- router: mu/var -> tilde -> top4 + renorm softmax ----------------
__global__ __launch_bounds__(256) void router_kernel(
    const float* __restrict__ h, const float* __restrict__ W_mu,
    const float* __restrict__ b_mu, const float* __restrict__ expW,
    const float* __restrict__ expb,
    int* __restrict__ topk_idx, float* __restrict__ topk_w,
    __hip_bfloat16* __restrict__ hb)
{
  __shared__ __align__(16) float hs[NF], hs2[NF];
  __shared__ float smu[NEXP], svar[NEXP];
  const int b = blockIdx.x, tid = threadIdx.x;
  for (int i = tid; i < NF; i += 256) {
    float v = h[(size_t)b * NF + i];
    hs[i] = v; hs2[i] = v * v;
    hb[(size_t)b * NF + i] = __float2bfloat16(v);
  }
  __syncthreads();
  const int e = tid >> 4, l = tid & 15;
  float mu = 0.f, var = 0.f;
  const float4* wm4 = (const float4*)(W_mu + e * NF);
  const float4* wv4 = (const float4*)(expW + e * NF);
  const float4* h4  = (const float4*)hs;
  const float4* h24 = (const float4*)hs2;
#pragma unroll
  for (int j = 0; j < NF / 64; ++j) {
    int i4 = l + j * 16;
    float4 a = h4[i4],  wa = wm4[i4];
    float4 c = h24[i4], wc = wv4[i4];
    mu  += a.x * wa.x + a.y * wa.y + a.z * wa.z + a.w * wa.w;
    var += c.x * wc.x + c.y * wc.y + c.z * wc.z + c.w * wc.w;
  }
#pragma unroll
  for (int o = 1; o < 16; o <<= 1) { mu += __shfl_xor(mu, o); var += __shfl_xor(var, o); }
  if (l == 0) { smu[e] = mu + b_mu[e]; svar[e] = var + expb[e]; }
  __syncthreads();
  if (tid < 64) {
    float val = -1e30f;
    if (tid < NEXP) {
      float v = fmaxf(svar[tid], 1e-12f);
      val = smu[tid] / sqrtf(1.0f + 0.39269908169872414f * v);  // pi/8
    }
    float mx = 0.f, wsum = 0.f;
    int i0, i1, i2, i3; float p0, p1, p2, p3;
#define TOPK_ROUND(ii, pp, FIRST)                                          \
    {                                                                      \
      float m = val;                                                       \
      m = fmaxf(m, __shfl_xor(m, 1));  m = fmaxf(m, __shfl_xor(m, 2));     \
      m = fmaxf(m, __shfl_xor(m, 4));  m = fmaxf(m, __shfl_xor(m, 8));     \
      m = fmaxf(m, __shfl_xor(m, 16)); m = fmaxf(m, __shfl_xor(m, 32));    \
      unsigned long long bm = __ballot(val == m);                          \
      int bi = (int)__builtin_ctzll(bm);                                   \
      if (FIRST) mx = m;                                                   \
      pp = expf(m - mx); wsum += pp; ii = bi;                              \
      if (tid == bi) val = -1e30f;                                         \
    }
    TOPK_ROUND(i0, p0, 1)
    TOPK_ROUND(i1, p1, 0)
    TOPK_ROUND(i2, p2, 0)
    TOPK_ROUND(i3, p3, 0)
#undef TOPK_ROUND
    if (tid == 0) {
      float inv = 1.0f / fmaxf(wsum, 1e-12f);
      topk_idx[b * 4 + 0] = i0; topk_w[b * 4 + 0] = p0 * inv;
      topk_idx[b * 4 + 1] = i1; topk_w[b * 4 + 1] = p1 * inv;
      topk_idx[b * 4 + 2] = i2; topk_w[b * 4 + 2] = p2 * inv;
      topk_idx[b * 4 + 3] = i3; topk_w[b * 4 + 3] = p3 * inv;
    }
  }
}

// ---------------- per-expert count (no atomics) ----------------
__global__ __launch_bounds__(256) void count_kernel(
    const int* __restrict__ topk_idx, int* __restrict__ counts)
{
  const int e = blockIdx.x;
  int c = 0;
  for (int i = threadIdx.x; i < NPAIR; i += 256) c += (topk_idx[i] == e);
#pragma unroll
  for (int o = 1; o < 64; o <<= 1) c += __shfl_xor(c, o);
  __shared__ int ws[4];
  if ((threadIdx.x & 63) == 0) ws[threadIdx.x >> 6] = c;
  __syncthreads();
  if (threadIdx.x == 0) counts[e] = ws[0] + ws[1] + ws[2] + ws[3];
}

__global__ void offsets_kernel(const int* __restrict__ counts, int* __restrict__ offsets) {
  if (threadIdx.x == 0) {
    int run = 0;
    for (int e = 0; e < NEXP; ++e) { offsets[e] = run; run += counts[e]; }
  }
}

// ---------------- stable scatter (deterministic, no atomics) ----------------
__global__ __launch_bounds__(256) void scatter_kernel(
    const int* __restrict__ topk_idx, const float* __restrict__ topk_w,
    const int* __restrict__ offsets,
    int* __restrict__ token_of_row, float* __restrict__ row_w)
{
  const int e = blockIdx.x;
  __shared__ int wsum[4];
  __shared__ int chunk_base;
  if (threadIdx.x == 0) chunk_base = offsets[e];
  __syncthreads();
  const int wid = threadIdx.x >> 6, lane = threadIdx.x & 63;
  for (int c0 = 0; c0 < NPAIR; c0 += 256) {
    const int t = c0 + threadIdx.x;
    const bool f = (topk_idx[t] == e);
    const unsigned long long m = __ballot(f);
    const int pre = __popcll(m & ((1ull << lane) - 1ull));
    if (lane == 0) wsum[wid] = __popcll(m);
    __syncthreads();
    int wbase = 0;
#pragma unroll
    for (int i = 0; i < 4; ++i) if (i < wid) wbase += wsum[i];
    const int total = wsum[0] + wsum[1] + wsum[2] + wsum[3];
    if (f) {
      const int pos = chunk_base + wbase + pre;
      token_of_row[pos] = t >> 2;
      row_w[pos] = topk_w[t];
    }
    __syncthreads();
    if (threadIdx.x == 0) chunk_base += total;
  }
}

// ---------------- weight transpose+convert: [E][R][C] f32 -> [E][C][R] bf16 ----------------
__global__ __launch_bounds__(256) void transpose_convert_kernel(
    const float* __restrict__ in, __hip_bfloat16* __restrict__ out, int R, int C)
{
  __shared__ float tile[32][33];
  const int e = blockIdx.z;
  const int r0 = blockIdx.y * 32, c0 = blockIdx.x * 32;
  const int x = threadIdx.x & 31, y = threadIdx.x >> 5;   // y: 0..7
  const float* ip = in + ((size_t)e * R + r0) * C + c0;
#pragma unroll
  for (int i = 0; i < 4; ++i) tile[y + 8 * i][x] = ip[(size_t)(y + 8 * i) * C + x];
  __syncthreads();
  __hip_bfloat16* op = out + ((size_t)e * C + c0) * R + r0;
#pragma unroll
  for (int i = 0; i < 4; ++i) op[(size_t)(y + 8 * i) * R + x] = __float2bfloat16(tile[x][y + 8 * i]);
}

// ================= 128x128 double-buffered 2-phase grouped GEMM =================
// BM=BN=128, BK=64, 4 waves, wave owns 64x64 (4x4 frags of 16x16x32).
// Per-iter: STAGE(next tile) -> compute(cur) -> vmcnt(0) -> s_barrier (T3 minimum 2-phase).

// ---------------- GEMM1: a = relu(h @ W1 + b1), gathered rows ----------------
__global__ __launch_bounds__(256) void gemm1_kernel(
    const __hip_bfloat16* __restrict__ hb,   // [NTOK, NF]
    const __hip_bfloat16* __restrict__ W1t,  // [E, NH, NF]  (n-major)
    const float* __restrict__ b1,            // [E, NH]
    const int* __restrict__ token_of_row, const int* __restrict__ offsets,
    const int* __restrict__ counts,
    __hip_bfloat16* __restrict__ a_out)      // [NPAIR, NH]
{
  const int e  = blockIdx.z;
  const int m0 = blockIdx.y * 128;
  const int n0 = blockIdx.x * 128;
  const int cnt = counts[e];
  if (m0 >= cnt) return;
  const int off = offsets[e];

  __shared__ __align__(16) __hip_bfloat16 As[2][8192]; // 2 x 16 KB
  __shared__ __align__(16) __hip_bfloat16 Bs[2][8192];

  const int tid = threadIdx.x;
  const int w = tid >> 6, l = tid & 63;
  const int wm = w >> 1, wn = w & 1;
  const int r16 = l & 15, g4 = l >> 4;

  int rA0 = off + m0 + l;       if (rA0 > NPAIR - 1) rA0 = NPAIR - 1;
  int rA1 = off + m0 + 64 + l;  if (rA1 > NPAIR - 1) rA1 = NPAIR - 1;
  const __hip_bfloat16* Ag0 = hb + (size_t)token_of_row[rA0] * NF + 2 * w * 8;
  const __hip_bfloat16* Ag1 = hb + (size_t)token_of_row[rA1] * NF + 2 * w * 8;
  const __hip_bfloat16* Bg0 = W1t + ((size_t)e * NH + n0 + l) * NF + 2 * w * 8;
  const __hip_bfloat16* Bg1 = W1t + ((size_t)e * NH + n0 + 64 + l) * NF + 2 * w * 8;

#define STAGE1(buf, k0)                                         \
  {                                                             \
    __hip_bfloat16* As0 = &As[buf][(2 * w) * 1024];             \
    __hip_bfloat16* Bs0 = &Bs[buf][(2 * w) * 1024];             \
    gload16_lds(Ag0 + (k0),      As0);                          \
    gload16_lds(Ag1 + (k0),      As0 + 512);                    \
    gload16_lds(Ag0 + (k0) + 8,  As0 + 1024);                   \
    gload16_lds(Ag1 + (k0) + 8,  As0 + 1536);                   \
    gload16_lds(Bg0 + (k0),      Bs0);                          \
    gload16_lds(Bg1 + (k0),      Bs0 + 512);                    \
    gload16_lds(Bg0 + (k0) + 8,  Bs0 + 1024);                   \
    gload16_lds(Bg1 + (k0) + 8,  Bs0 + 1536);                   \
  }

  f32x4 acc[4][4] = {};
  const int NT = NF / 64;  // 8

  STAGE1(0, 0)
  asm volatile("s_waitcnt vmcnt(0)" ::: "memory");
  __builtin_amdgcn_s_barrier();
  __builtin_amdgcn_sched_barrier(0);

  int cur = 0;
  for (int t = 0; t < NT; ++t) {
    if (t + 1 < NT) STAGE1(cur ^ 1, (t + 1) * 64)
    __builtin_amdgcn_sched_barrier(0);
#pragma unroll
    for (int ks = 0; ks < 2; ++ks) {
      const int g = ks * 4 + g4;
      bf16x8 af[4], bq[4];
#pragma unroll
      for (int rr = 0; rr < 4; ++rr)
        af[rr] = *(const bf16x8*)(&As[cur][(g * 128 + wm * 64 + rr * 16 + r16) * 8]);
#pragma unroll
      for (int nn = 0; nn < 4; ++nn)
        bq[nn] = *(const bf16x8*)(&Bs[cur][(g * 128 + wn * 64 + nn * 16 + r16) * 8]);
#pragma unroll
      for (int rr = 0; rr < 4; ++rr)
#pragma unroll
        for (int nn = 0; nn < 4; ++nn)
          acc[rr][nn] = __builtin_amdgcn_mfma_f32_16x16x32_bf16(af[rr], bq[nn], acc[rr][nn], 0, 0, 0);
    }
    __builtin_amdgcn_sched_barrier(0);
    if (t + 1 < NT) {
      asm volatile("s_waitcnt vmcnt(0)" ::: "memory");
      __builtin_amdgcn_s_barrier();
      __builtin_amdgcn_sched_barrier(0);
    }
    cur ^= 1;
  }

  const int q4 = l >> 4, cl = l & 15;
  const int mmax = cnt - m0;
#pragma unroll
  for (int rr = 0; rr < 4; ++rr) {
#pragma unroll
    for (int nn = 0; nn < 4; ++nn) {
      const int c = n0 + wn * 64 + nn * 16 + cl;
      const float bias = b1[e * NH + c];
#pragma unroll
      for (int q = 0; q < 4; ++q) {
        const int r = wm * 64 + rr * 16 + q4 * 4 + q;
        if (r < mmax) {
          float v = fmaxf(acc[rr][nn][q] + bias, 0.f);
          a_out[(size_t)(off + m0 + r) * NH + c] = __float2bfloat16(v);
        }
      }
    }
  }
#undef STAGE1
}

// ---------------- GEMM2: out += w * (a @ W2 + b2), K-split x2, fused scatter ----------------
__global__ __launch_bounds__(256) void gemm2_kernel(
    const __hip_bfloat16* __restrict__ a_in,  // [NPAIR, NH]
    const __hip_bfloat16* __restrict__ W2t,   // [E, NCOUT, NH] (n-major)
    const float* __restrict__ b2,             // [E, NCOUT]
    const int* __restrict__ token_of_row, const float* __restrict__ row_w,
    const int* __restrict__ offsets, const int* __restrict__ counts,
    float* __restrict__ out)                  // [NTOK, NCOUT]
{
  const int e  = blockIdx.z >> 1;
  const int kc = blockIdx.z & 1;
  const int m0 = blockIdx.y * 128;
  const int n0 = blockIdx.x * 128;
  const int cnt = counts[e];
  if (m0 >= cnt) return;
  const int off = offsets[e];
  const int koff = kc * (NH / 2);

  __shared__ __align__(16) __hip_bfloat16 As[2][8192];
  __shared__ __align__(16) __hip_bfloat16 Bs[2][8192];

  const int tid = threadIdx.x;
  const int w = tid >> 6, l = tid & 63;
  const int wm = w >> 1, wn = w & 1;
  const int r16 = l & 15, g4 = l >> 4;

  int rA0 = off + m0 + l;       if (rA0 > NPAIR - 1) rA0 = NPAIR - 1;
  int rA1 = off + m0 + 64 + l;  if (rA1 > NPAIR - 1) rA1 = NPAIR - 1;
  const __hip_bfloat16* Ag0 = a_in + (size_t)rA0 * NH + koff + 2 * w * 8;
  const __hip_bfloat16* Ag1 = a_in + (size_t)rA1 * NH + koff + 2 * w * 8;
  const __hip_bfloat16* Bg0 = W2t + ((size_t)e * NCOUT + n0 + l) * NH + koff + 2 * w * 8;
  const __hip_bfloat16* Bg1 = W2t + ((size_t)e * NCOUT + n0 + 64 + l) * NH + koff + 2 * w * 8;

#define STAGE2(buf, k0)                                         \
  {                                                             \
    __hip_bfloat16* As0 = &As[buf][(2 * w) * 1024];             \
    __hip_bfloat16* Bs0 = &Bs[buf][(2 * w) * 1024];             \
    gload16_lds(Ag0 + (k0),      As0);                          \
    gload16_lds(Ag1 + (k0),      As0 + 512);                    \
    gload16_lds(Ag0 + (k0) + 8,  As0 + 1024);                   \
    gload16_lds(Ag1 + (k0) + 8,  As0 + 1536);                   \
    gload16_lds(Bg0 + (k0),      Bs0);                          \
    gload16_lds(Bg1 + (k0),      Bs0 + 512);                    \
    gload16_lds(Bg0 + (k0) + 8,  Bs0 + 1024);                   \
    gload16_lds(Bg1 + (k0) + 8,  Bs0 + 1536);                   \
  }

  f32x4 acc[4][4] = {};
  const int NT = (NH / 2) / 64;  // 8

  STAGE2(0, 0)
  asm volatile("s_waitcnt vmcnt(0)" ::: "memory");
  __builtin_amdgcn_s_barrier();
  __builtin_amdgcn_sched_barrier(0);

  int cur = 0;
  for (int t = 0; t < NT; ++t) {
    if (t + 1 < NT) STAGE2(cur ^ 1, (t + 1) * 64)
    __builtin_amdgcn_sched_barrier(0);
#pragma unroll
    for (int ks = 0; ks < 2; ++ks) {
      const int g = ks * 4 + g4;
      bf16x8 af[4], bq[4];
#pragma unroll
      for (int rr = 0; rr < 4; ++rr)
        af[rr] = *(const bf16x8*)(&As[cur][(g * 128 + wm * 64 + rr * 16 + r16) * 8]);
#pragma unroll
      for (int nn = 0; nn < 4; ++nn)
        bq[nn] = *(const bf16x8*)(&Bs[cur][(g * 128 + wn * 64 + nn * 16 + r16) * 8]);
#pragma unroll
      for (int rr = 0; rr < 4; ++rr)
#pragma unroll
        for (int nn = 0; nn < 4; ++nn)
          acc[rr][nn] = __builtin_amdgcn_mfma_f32_16x16x32_bf16(af[rr], bq[nn], acc[rr][nn], 0, 0, 0);
    }
    __builtin_amdgcn_sched_barrier(0);
    if (t + 1 < NT) {
      asm volatile("s_waitcnt vmcnt(0)" ::: "memory");
      __builtin_amdgcn_s_barrier();
      __builtin_amdgcn_sched_barrier(0);
    }
    cur ^= 1;
  }

  const int q4 = l >> 4, cl = l & 15;
  const int mmax = cnt - m0;
#pragma unroll
  for (int rr = 0; rr < 4; ++rr) {
#pragma unroll
    for (int nn = 0; nn < 4; ++nn) {
      const int c = n0 + wn * 64 + nn * 16 + cl;
      const float bias = (kc == 0) ? b2[e * NCOUT + c] : 0.f;
#pragma unroll
      for (int q = 0; q < 4; ++q) {
        const int r = wm * 64 + rr * 16 + q4 * 4 + q;
        if (r < mmax) {
          const int grow = off + m0 + r;
          const int tok = token_of_row[grow];
          const float wt = row_w[grow];
          atomicAdd(&out[(size_t)tok * NCOUT + c], wt * (acc[rr][nn][q] + bias));
        }
      }
    }
  }
#undef STAGE2
}

extern "C" void kernel_launch(void* const* d_in, const int* in_sizes, int n_in,
                              void* d_out, int out_size, void* d_ws, size_t ws_size,
                              hipStream_t stream) {
  (void)in_sizes; (void)n_in; (void)ws_size;
  const float* h        = (const float*)d_in[0];
  const float* W_mu     = (const float*)d_in[1];
  const float* b_mu     = (const float*)d_in[2];
  const float* W_logvar = (const float*)d_in[3];
  const float* b_logvar = (const float*)d_in[4];
  const float* W1       = (const float*)d_in[5];
  const float* b1       = (const float*)d_in[6];
  const float* W2       = (const float*)d_in[7];
  const float* b2       = (const float*)d_in[8];
  float* out = (float*)d_out;

  char* p = (char*)d_ws;
  int*   counts   = (int*)p;   p += 16 * 4;
  int*   offsets  = (int*)p;   p += 16 * 4;
  float* expb     = (float*)p; p += 16 * 4;
  p += 16 * 4; // pad
  float* expW     = (float*)p; p += (size_t)NEXP * NF * 4;
  int*   topk_idx = (int*)p;   p += (size_t)NPAIR * 4;
  float* topk_w   = (float*)p; p += (size_t)NPAIR * 4;
  int*   tok_row  = (int*)p;   p += (size_t)NPAIR * 4;
  float* row_w    = (float*)p; p += (size_t)NPAIR * 4;
  __hip_bfloat16* hb   = (__hip_bfloat16*)p; p += (size_t)NTOK * NF * 2;
  __hip_bfloat16* W1t  = (__hip_bfloat16*)p; p += (size_t)NEXP * NF * NH * 2;
  __hip_bfloat16* W2t  = (__hip_bfloat16*)p; p += (size_t)NEXP * NH * NCOUT * 2;
  __hip_bfloat16* abuf = (__hip_bfloat16*)p; p += (size_t)NPAIR * NH * 2;

  hipMemsetAsync(d_out, 0, (size_t)out_size * 4, stream);

  precompute_kernel<<<(NEXP * NF + 255) / 256, 256, 0, stream>>>(W_logvar, b_logvar, expW, expb);
  router_kernel<<<NTOK, 256, 0, stream>>>(h, W_mu, b_mu, expW, expb, topk_idx, topk_w, hb);
  count_kernel<<<NEXP, 256, 0, stream>>>(topk_idx, counts);
  offsets_kernel<<<1, 64, 0, stream>>>(counts, offsets);
  scatter_kernel<<<NEXP, 256, 0, stream>>>(topk_idx, topk_w, offsets, tok_row, row_w);

  transpose_convert_kernel<<<dim3(NH / 32, NF / 32, NEXP), 256, 0, stream>>>(W1, W1t, NF, NH);
  transpose_convert_kernel<<<dim3(NCOUT / 32, NH / 32, NEXP), 256, 0, stream>>>(W2, W2t, NH, NCOUT);

  gemm1_kernel<<<dim3(NH / 128, NTOK / 128, NEXP), 256, 0, stream>>>(
      hb, W1t, b1, tok_row, offsets, counts, abuf);
  gemm2_kernel<<<dim3(NCOUT / 128, NTOK / 128, NEXP * 2), 256, 0, stream>>>(
      abuf, W2t, b2, tok_row, row_w, offsets, counts, out);
}

// Round 5
// 158.185 us; speedup vs baseline: 1.2446x; 1.2446x over previous
//
#include <hip/hip_runtime.h>
#include <hip/hip_bf16.h>

typedef __attribute__((ext_vector_type(8))) short bf16x8;
typedef __attribute__((ext_vector_type(4))) float f32x4;

#define NTOK   2048
#define NEXP   16
#define NF     512
#define NH     1024
#define NCOUT  512
#define NPAIR  8192   // NTOK * 4

__device__ __forceinline__ void gload16_lds(const __hip_bfloat16* g, __hip_bfloat16* l) {
  __builtin_amdgcn_global_load_lds((const __attribute__((address_space(1))) void*)g,
                                   (__attribute__((address_space(3))) void*)l, 16, 0, 0);
}

// ---------------- precompute exp(W_logvar), exp(b_logvar) ----------------
__global__ __launch_bounds__(256) void precompute_kernel(
    const float* __restrict__ W_logvar, const float* __restrict__ b_logvar,
    float* __restrict__ expW, float* __restrict__ expb)
{
  int i = blockIdx.x * 256 + threadIdx.x;
  if (i < NEXP * NF) expW[i] = expf(W_logvar[i]);
  if (i < NEXP) expb[i] = expf(b_logvar[i]);
}

// ---------------- router: mu/var -> tilde -> top4 + renorm softmax ----------------
__global__ __launch_bounds__(256) void router_kernel(
    const float* __restrict__ h, const float* __restrict__ W_mu,
    const float* __restrict__ b_mu, const float* __restrict__ expW,
    const float* __restrict__ expb,
    int* __restrict__ topk_idx, float* __restrict__ topk_w,
    __hip_bfloat16* __restrict__ hb)
{
  __shared__ __align__(16) float hs[NF], hs2[NF];
  __shared__ float smu[NEXP], svar[NEXP];
  const int b = blockIdx.x, tid = threadIdx.x;
  for (int i = tid; i < NF; i += 256) {
    float v = h[(size_t)b * NF + i];
    hs[i] = v; hs2[i] = v * v;
    hb[(size_t)b * NF + i] = __float2bfloat16(v);
  }
  __syncthreads();
  const int e = tid >> 4, l = tid & 15;
  float mu = 0.f, var = 0.f;
  const float4* wm4 = (const float4*)(W_mu + e * NF);
  const float4* wv4 = (const float4*)(expW + e * NF);
  const float4* h4  = (const float4*)hs;
  const float4* h24 = (const float4*)hs2;
#pragma unroll
  for (int j = 0; j < NF / 64; ++j) {
    int i4 = l + j * 16;
    float4 a = h4[i4],  wa = wm4[i4];
    float4 c = h24[i4], wc = wv4[i4];
    mu  += a.x * wa.x + a.y * wa.y + a.z * wa.z + a.w * wa.w;
    var += c.x * wc.x + c.y * wc.y + c.z * wc.z + c.w * wc.w;
  }
#pragma unroll
  for (int o = 1; o < 16; o <<= 1) { mu += __shfl_xor(mu, o); var += __shfl_xor(var, o); }
  if (l == 0) { smu[e] = mu + b_mu[e]; svar[e] = var + expb[e]; }
  __syncthreads();
  if (tid < 64) {
    float val = -1e30f;
    if (tid < NEXP) {
      float v = fmaxf(svar[tid], 1e-12f);
      val = smu[tid] / sqrtf(1.0f + 0.39269908169872414f * v);  // pi/8
    }
    float mx = 0.f, wsum = 0.f;
    int i0, i1, i2, i3; float p0, p1, p2, p3;
#define TOPK_ROUND(ii, pp, FIRST)                                          \
    {                                                                      \
      float m = val;                                                       \
      m = fmaxf(m, __shfl_xor(m, 1));  m = fmaxf(m, __shfl_xor(m, 2));     \
      m = fmaxf(m, __shfl_xor(m, 4));  m = fmaxf(m, __shfl_xor(m, 8));     \
      m = fmaxf(m, __shfl_xor(m, 16)); m = fmaxf(m, __shfl_xor(m, 32));    \
      unsigned long long bm = __ballot(val == m);                          \
      int bi = (int)__builtin_ctzll(bm);                                   \
      if (FIRST) mx = m;                                                   \
      pp = expf(m - mx); wsum += pp; ii = bi;                              \
      if (tid == bi) val = -1e30f;                                         \
    }
    TOPK_ROUND(i0, p0, 1)
    TOPK_ROUND(i1, p1, 0)
    TOPK_ROUND(i2, p2, 0)
    TOPK_ROUND(i3, p3, 0)
#undef TOPK_ROUND
    if (tid == 0) {
      float inv = 1.0f / fmaxf(wsum, 1e-12f);
      topk_idx[b * 4 + 0] = i0; topk_w[b * 4 + 0] = p0 * inv;
      topk_idx[b * 4 + 1] = i1; topk_w[b * 4 + 1] = p1 * inv;
      topk_idx[b * 4 + 2] = i2; topk_w[b * 4 + 2] = p2 * inv;
      topk_idx[b * 4 + 3] = i3; topk_w[b * 4 + 3] = p3 * inv;
    }
  }
}

// ---------------- per-expert count (no atomics) ----------------
__global__ __launch_bounds__(256) void count_kernel(
    const int* __restrict__ topk_idx, int* __restrict__ counts)
{
  const int e = blockIdx.x;
  int c = 0;
  for (int i = threadIdx.x; i < NPAIR; i += 256) c += (topk_idx[i] == e);
#pragma unroll
  for (int o = 1; o < 64; o <<= 1) c += __shfl_xor(c, o);
  __shared__ int ws[4];
  if ((threadIdx.x & 63) == 0) ws[threadIdx.x >> 6] = c;
  __syncthreads();
  if (threadIdx.x == 0) counts[e] = ws[0] + ws[1] + ws[2] + ws[3];
}

__global__ void offsets_kernel(const int* __restrict__ counts, int* __restrict__ offsets) {
  if (threadIdx.x == 0) {
    int run = 0;
    for (int e = 0; e < NEXP; ++e) { offsets[e] = run; run += counts[e]; }
  }
}

// ---------------- stable scatter (deterministic, no atomics) ----------------
__global__ __launch_bounds__(256) void scatter_kernel(
    const int* __restrict__ topk_idx, const float* __restrict__ topk_w,
    const int* __restrict__ offsets,
    int* __restrict__ token_of_row, float* __restrict__ row_w)
{
  const int e = blockIdx.x;
  __shared__ int wsum[4];
  __shared__ int chunk_base;
  if (threadIdx.x == 0) chunk_base = offsets[e];
  __syncthreads();
  const int wid = threadIdx.x >> 6, lane = threadIdx.x & 63;
  for (int c0 = 0; c0 < NPAIR; c0 += 256) {
    const int t = c0 + threadIdx.x;
    const bool f = (topk_idx[t] == e);
    const unsigned long long m = __ballot(f);
    const int pre = __popcll(m & ((1ull << lane) - 1ull));
    if (lane == 0) wsum[wid] = __popcll(m);
    __syncthreads();
    int wbase = 0;
#pragma unroll
    for (int i = 0; i < 4; ++i) if (i < wid) wbase += wsum[i];
    const int total = wsum[0] + wsum[1] + wsum[2] + wsum[3];
    if (f) {
      const int pos = chunk_base + wbase + pre;
      token_of_row[pos] = t >> 2;
      row_w[pos] = topk_w[t];
    }
    __syncthreads();
    if (threadIdx.x == 0) chunk_base += total;
  }
}

// ---------------- weight transpose+convert: [E][R][C] f32 -> [E][C][R] bf16 ----------------
__global__ __launch_bounds__(256) void transpose_convert_kernel(
    const float* __restrict__ in, __hip_bfloat16* __restrict__ out, int R, int C)
{
  __shared__ float tile[32][33];
  const int e = blockIdx.z;
  const int r0 = blockIdx.y * 32, c0 = blockIdx.x * 32;
  const int x = threadIdx.x & 31, y = threadIdx.x >> 5;   // y: 0..7
  const float* ip = in + ((size_t)e * R + r0) * C + c0;
#pragma unroll
  for (int i = 0; i < 4; ++i) tile[y + 8 * i][x] = ip[(size_t)(y + 8 * i) * C + x];
  __syncthreads();
  __hip_bfloat16* op = out + ((size_t)e * C + c0) * R + r0;
#pragma unroll
  for (int i = 0; i < 4; ++i) op[(size_t)(y + 8 * i) * R + x] = __float2bfloat16(tile[x][y + 8 * i]);
}

// ================= 128x64 grouped GEMM, 4 waves (wave = 64x32), BK=64 =================
// LDS: A [g:8][128][8] = 16KB, B [g:8][64][8] = 8KB -> 24KB/block, ~4+ blocks/CU.
// Simple 2-barrier loop; latency hidden by co-resident blocks (m114).
// 1D grid, XCD-chunked swizzle: logical = (bid%8)*(total/8) + bid/8 (total%8==0).

// ---------------- GEMM1: a = relu(h @ W1 + b1), gathered rows ----------------
// logical id = e*256 + m*16 + n   (n: 16 x 64-col blocks, m: 16 x 128-row blocks)
__global__ __launch_bounds__(256) void gemm1_kernel(
    const __hip_bfloat16* __restrict__ hb,   // [NTOK, NF]
    const __hip_bfloat16* __restrict__ W1t,  // [E, NH, NF]  (n-major)
    const float* __restrict__ b1,            // [E, NH]
    const int* __restrict__ token_of_row, const int* __restrict__ offsets,
    const int* __restrict__ counts,
    __hip_bfloat16* __restrict__ a_out)      // [NPAIR, NH]
{
  const int bid = blockIdx.x;                      // 4096 blocks
  const int id  = (bid & 7) * 512 + (bid >> 3);    // XCD-chunked
  const int e   = id >> 8;
  const int m0  = ((id >> 4) & 15) * 128;
  const int n0  = (id & 15) * 64;
  const int cnt = counts[e];
  if (m0 >= cnt) return;
  const int off = offsets[e];

  __shared__ __align__(16) __hip_bfloat16 As[8192]; // [g:8][row:128][8]
  __shared__ __align__(16) __hip_bfloat16 Bs[4096]; // [g:8][row:64][8]

  const int tid = threadIdx.x;
  const int w = tid >> 6, l = tid & 63;
  const int wm = w >> 1, wn = w & 1;
  const int r16 = l & 15, g4 = l >> 4;

  int rA0 = off + m0 + l;       if (rA0 > NPAIR - 1) rA0 = NPAIR - 1;
  int rA1 = off + m0 + 64 + l;  if (rA1 > NPAIR - 1) rA1 = NPAIR - 1;
  const __hip_bfloat16* AgL = hb + (size_t)token_of_row[rA0] * NF;
  const __hip_bfloat16* AgH = hb + (size_t)token_of_row[rA1] * NF;
  const __hip_bfloat16* Bg  = W1t + ((size_t)e * NH + n0 + l) * NF;
  const int g0 = 2 * w;
  __hip_bfloat16* AsD = As + g0 * 1024;   // g0 row-block base (128 rows * 8)
  __hip_bfloat16* BsD = Bs + g0 * 512;    // (64 rows * 8)

  f32x4 acc[4][2] = {};

  for (int k0 = 0; k0 < NF; k0 += 64) {
    __syncthreads();
    gload16_lds(AgL + k0 + g0 * 8,       AsD);
    gload16_lds(AgH + k0 + g0 * 8,       AsD + 512);
    gload16_lds(AgL + k0 + (g0 + 1) * 8, AsD + 1024);
    gload16_lds(AgH + k0 + (g0 + 1) * 8, AsD + 1536);
    gload16_lds(Bg + k0 + g0 * 8,        BsD);
    gload16_lds(Bg + k0 + (g0 + 1) * 8,  BsD + 512);
    __syncthreads();
#pragma unroll
    for (int ks = 0; ks < 2; ++ks) {
      const int g = ks * 4 + g4;
      bf16x8 af[4], bq[2];
#pragma unroll
      for (int rr = 0; rr < 4; ++rr)
        af[rr] = *(const bf16x8*)(As + (g * 128 + wm * 64 + rr * 16 + r16) * 8);
#pragma unroll
      for (int nn = 0; nn < 2; ++nn)
        bq[nn] = *(const bf16x8*)(Bs + (g * 64 + wn * 32 + nn * 16 + r16) * 8);
#pragma unroll
      for (int rr = 0; rr < 4; ++rr)
#pragma unroll
        for (int nn = 0; nn < 2; ++nn)
          acc[rr][nn] = __builtin_amdgcn_mfma_f32_16x16x32_bf16(af[rr], bq[nn], acc[rr][nn], 0, 0, 0);
    }
  }

  const int q4 = l >> 4, cl = l & 15;
  const int mmax = cnt - m0;
#pragma unroll
  for (int rr = 0; rr < 4; ++rr) {
#pragma unroll
    for (int nn = 0; nn < 2; ++nn) {
      const int c = n0 + wn * 32 + nn * 16 + cl;
      const float bias = b1[e * NH + c];
#pragma unroll
      for (int q = 0; q < 4; ++q) {
        const int r = wm * 64 + rr * 16 + q4 * 4 + q;
        if (r < mmax) {
          float v = fmaxf(acc[rr][nn][q] + bias, 0.f);
          a_out[(size_t)(off + m0 + r) * NH + c] = __float2bfloat16(v);
        }
      }
    }
  }
}

// ---------------- GEMM2: out += w * (a @ W2 + b2), K-split x2, fused scatter ----------------
// logical id = e*256 + m*16 + kc*8 + n   (n: 8 x 64-col, m: 16 x 128-row, kc: K half)
__global__ __launch_bounds__(256) void gemm2_kernel(
    const __hip_bfloat16* __restrict__ a_in,  // [NPAIR, NH]
    const __hip_bfloat16* __restrict__ W2t,   // [E, NCOUT, NH] (n-major)
    const float* __restrict__ b2,             // [E, NCOUT]
    const int* __restrict__ token_of_row, const float* __restrict__ row_w,
    const int* __restrict__ offsets, const int* __restrict__ counts,
    float* __restrict__ out)                  // [NTOK, NCOUT]
{
  const int bid = blockIdx.x;                      // 4096 blocks
  const int id  = (bid & 7) * 512 + (bid >> 3);
  const int e   = id >> 8;
  const int m0  = ((id >> 4) & 15) * 128;
  const int kc  = (id >> 3) & 1;
  const int n0  = (id & 7) * 64;
  const int cnt = counts[e];
  if (m0 >= cnt) return;
  const int off = offsets[e];
  const int koff = kc * (NH / 2);

  __shared__ __align__(16) __hip_bfloat16 As[8192];
  __shared__ __align__(16) __hip_bfloat16 Bs[4096];

  const int tid = threadIdx.x;
  const int w = tid >> 6, l = tid & 63;
  const int wm = w >> 1, wn = w & 1;
  const int r16 = l & 15, g4 = l >> 4;

  int rA0 = off + m0 + l;       if (rA0 > NPAIR - 1) rA0 = NPAIR - 1;
  int rA1 = off + m0 + 64 + l;  if (rA1 > NPAIR - 1) rA1 = NPAIR - 1;
  const __hip_bfloat16* AgL = a_in + (size_t)rA0 * NH + koff;
  const __hip_bfloat16* AgH = a_in + (size_t)rA1 * NH + koff;
  const __hip_bfloat16* Bg  = W2t + ((size_t)e * NCOUT + n0 + l) * NH + koff;
  const int g0 = 2 * w;
  __hip_bfloat16* AsD = As + g0 * 1024;
  __hip_bfloat16* BsD = Bs + g0 * 512;

  f32x4 acc[4][2] = {};

  for (int k0 = 0; k0 < NH / 2; k0 += 64) {
    __syncthreads();
    gload16_lds(AgL + k0 + g0 * 8,       AsD);
    gload16_lds(AgH + k0 + g0 * 8,       AsD + 512);
    gload16_lds(AgL + k0 + (g0 + 1) * 8, AsD + 1024);
    gload16_lds(AgH + k0 + (g0 + 1) * 8, AsD + 1536);
    gload16_lds(Bg + k0 + g0 * 8,        BsD);
    gload16_lds(Bg + k0 + (g0 + 1) * 8,  BsD + 512);
    __syncthreads();
#pragma unroll
    for (int ks = 0; ks < 2; ++ks) {
      const int g = ks * 4 + g4;
      bf16x8 af[4], bq[2];
#pragma unroll
      for (int rr = 0; rr < 4; ++rr)
        af[rr] = *(const bf16x8*)(As + (g * 128 + wm * 64 + rr * 16 + r16) * 8);
#pragma unroll
      for (int nn = 0; nn < 2; ++nn)
        bq[nn] = *(const bf16x8*)(Bs + (g * 64 + wn * 32 + nn * 16 + r16) * 8);
#pragma unroll
      for (int rr = 0; rr < 4; ++rr)
#pragma unroll
        for (int nn = 0; nn < 2; ++nn)
          acc[rr][nn] = __builtin_amdgcn_mfma_f32_16x16x32_bf16(af[rr], bq[nn], acc[rr][nn], 0, 0, 0);
    }
  }

  const int q4 = l >> 4, cl = l & 15;
  const int mmax = cnt - m0;
#pragma unroll
  for (int rr = 0; rr < 4; ++rr) {
#pragma unroll
    for (int nn = 0; nn < 2; ++nn) {
      const int c = n0 + wn * 32 + nn * 16 + cl;
      const float bias = (kc == 0) ? b2[e * NCOUT + c] : 0.f;
#pragma unroll
      for (int q = 0; q < 4; ++q) {
        const int r = wm * 64 + rr * 16 + q4 * 4 + q;
        if (r < mmax) {
          const int grow = off + m0 + r;
          const int tok = token_of_row[grow];
          const float wt = row_w[grow];
          atomicAdd(&out[(size_t)tok * NCOUT + c], wt * (acc[rr][nn][q] + bias));
        }
      }
    }
  }
}

extern "C" void kernel_launch(void* const* d_in, const int* in_sizes, int n_in,
                              void* d_out, int out_size, void* d_ws, size_t ws_size,
                              hipStream_t stream) {
  (void)in_sizes; (void)n_in; (void)ws_size;
  const float* h        = (const float*)d_in[0];
  const float* W_mu     = (const float*)d_in[1];
  const float* b_mu     = (const float*)d_in[2];
  const float* W_logvar = (const float*)d_in[3];
  const float* b_logvar = (const float*)d_in[4];
  const float* W1       = (const float*)d_in[5];
  const float* b1       = (const float*)d_in[6];
  const float* W2       = (const float*)d_in[7];
  const float* b2       = (const float*)d_in[8];
  float* out = (float*)d_out;

  char* p = (char*)d_ws;
  int*   counts   = (int*)p;   p += 16 * 4;
  int*   offsets  = (int*)p;   p += 16 * 4;
  float* expb     = (float*)p; p += 16 * 4;
  p += 16 * 4; // pad
  float* expW     = (float*)p; p += (size_t)NEXP * NF * 4;
  int*   topk_idx = (int*)p;   p += (size_t)NPAIR * 4;
  float* topk_w   = (float*)p; p += (size_t)NPAIR * 4;
  int*   tok_row  = (int*)p;   p += (size_t)NPAIR * 4;
  float* row_w    = (float*)p; p += (size_t)NPAIR * 4;
  __hip_bfloat16* hb   = (__hip_bfloat16*)p; p += (size_t)NTOK * NF * 2;
  __hip_bfloat16* W1t  = (__hip_bfloat16*)p; p += (size_t)NEXP * NF * NH * 2;
  __hip_bfloat16* W2t  = (__hip_bfloat16*)p; p += (size_t)NEXP * NH * NCOUT * 2;
  __hip_bfloat16* abuf = (__hip_bfloat16*)p; p += (size_t)NPAIR * NH * 2;

  hipMemsetAsync(d_out, 0, (size_t)out_size * 4, stream);

  precompute_kernel<<<(NEXP * NF + 255) / 256, 256, 0, stream>>>(W_logvar, b_logvar, expW, expb);
  router_kernel<<<NTOK, 256, 0, stream>>>(h, W_mu, b_mu, expW, expb, topk_idx, topk_w, hb);
  count_kernel<<<NEXP, 256, 0, stream>>>(topk_idx, counts);
  offsets_kernel<<<1, 64, 0, stream>>>(counts, offsets);
  scatter_kernel<<<NEXP, 256, 0, stream>>>(topk_idx, topk_w, offsets, tok_row, row_w);

  transpose_convert_kernel<<<dim3(NH / 32, NF / 32, NEXP), 256, 0, stream>>>(W1, W1t, NF, NH);
  transpose_convert_kernel<<<dim3(NCOUT / 32, NH / 32, NEXP), 256, 0, stream>>>(W2, W2t, NH, NCOUT);

  gemm1_kernel<<<4096, 256, 0, stream>>>(hb, W1t, b1, tok_row, offsets, counts, abuf);
  gemm2_kernel<<<4096, 256, 0, stream>>>(abuf, W2t, b2, tok_row, row_w, offsets, counts, out);
}

// Round 6
// 147.751 us; speedup vs baseline: 1.3325x; 1.0706x over previous
//
#include <hip/hip_runtime.h>
#include <hip/hip_bf16.h>

typedef __attribute__((ext_vector_type(8))) short bf16x8;
typedef __attribute__((ext_vector_type(4))) float f32x4;

#define NTOK   2048
#define NEXP   16
#define NF     512
#define NH     1024
#define NCOUT  512
#define NPAIR  8192   // NTOK * 4

__device__ __forceinline__ void gload16_lds(const __hip_bfloat16* g, __hip_bfloat16* l) {
  __builtin_amdgcn_global_load_lds((const __attribute__((address_space(1))) void*)g,
                                   (__attribute__((address_space(3))) void*)l, 16, 0, 0);
}

// ---------------- precompute exp(W_logvar), exp(b_logvar) ----------------
__global__ __launch_bounds__(256) void precompute_kernel(
    const float* __restrict__ W_logvar, const float* __restrict__ b_logvar,
    float* __restrict__ expW, float* __restrict__ expb)
{
  int i = blockIdx.x * 256 + threadIdx.x;
  if (i < NEXP * NF) expW[i] = expf(W_logvar[i]);
  if (i < NEXP) expb[i] = expf(b_logvar[i]);
}

// ---------------- router: mu/var -> tilde -> top4 + renorm softmax ----------------
__global__ __launch_bounds__(256) void router_kernel(
    const float* __restrict__ h, const float* __restrict__ W_mu,
    const float* __restrict__ b_mu, const float* __restrict__ expW,
    const float* __restrict__ expb,
    int* __restrict__ topk_idx, float* __restrict__ topk_w,
    __hip_bfloat16* __restrict__ hb)
{
  __shared__ __align__(16) float hs[NF], hs2[NF];
  __shared__ float smu[NEXP], svar[NEXP];
  const int b = blockIdx.x, tid = threadIdx.x;
  for (int i = tid; i < NF; i += 256) {
    float v = h[(size_t)b * NF + i];
    hs[i] = v; hs2[i] = v * v;
    hb[(size_t)b * NF + i] = __float2bfloat16(v);
  }
  __syncthreads();
  const int e = tid >> 4, l = tid & 15;
  float mu = 0.f, var = 0.f;
  const float4* wm4 = (const float4*)(W_mu + e * NF);
  const float4* wv4 = (const float4*)(expW + e * NF);
  const float4* h4  = (const float4*)hs;
  const float4* h24 = (const float4*)hs2;
#pragma unroll
  for (int j = 0; j < NF / 64; ++j) {
    int i4 = l + j * 16;
    float4 a = h4[i4],  wa = wm4[i4];
    float4 c = h24[i4], wc = wv4[i4];
    mu  += a.x * wa.x + a.y * wa.y + a.z * wa.z + a.w * wa.w;
    var += c.x * wc.x + c.y * wc.y + c.z * wc.z + c.w * wc.w;
  }
#pragma unroll
  for (int o = 1; o < 16; o <<= 1) { mu += __shfl_xor(mu, o); var += __shfl_xor(var, o); }
  if (l == 0) { smu[e] = mu + b_mu[e]; svar[e] = var + expb[e]; }
  __syncthreads();
  if (tid < 64) {
    float val = -1e30f;
    if (tid < NEXP) {
      float v = fmaxf(svar[tid], 1e-12f);
      val = smu[tid] / sqrtf(1.0f + 0.39269908169872414f * v);  // pi/8
    }
    float mx = 0.f, wsum = 0.f;
    int i0, i1, i2, i3; float p0, p1, p2, p3;
#define TOPK_ROUND(ii, pp, FIRST)                                          \
    {                                                                      \
      float m = val;                                                       \
      m = fmaxf(m, __shfl_xor(m, 1));  m = fmaxf(m, __shfl_xor(m, 2));     \
      m = fmaxf(m, __shfl_xor(m, 4));  m = fmaxf(m, __shfl_xor(m, 8));     \
      m = fmaxf(m, __shfl_xor(m, 16)); m = fmaxf(m, __shfl_xor(m, 32));    \
      unsigned long long bm = __ballot(val == m);                          \
      int bi = (int)__builtin_ctzll(bm);                                   \
      if (FIRST) mx = m;                                                   \
      pp = expf(m - mx); wsum += pp; ii = bi;                              \
      if (tid == bi) val = -1e30f;                                         \
    }
    TOPK_ROUND(i0, p0, 1)
    TOPK_ROUND(i1, p1, 0)
    TOPK_ROUND(i2, p2, 0)
    TOPK_ROUND(i3, p3, 0)
#undef TOPK_ROUND
    if (tid == 0) {
      float inv = 1.0f / fmaxf(wsum, 1e-12f);
      topk_idx[b * 4 + 0] = i0; topk_w[b * 4 + 0] = p0 * inv;
      topk_idx[b * 4 + 1] = i1; topk_w[b * 4 + 1] = p1 * inv;
      topk_idx[b * 4 + 2] = i2; topk_w[b * 4 + 2] = p2 * inv;
      topk_idx[b * 4 + 3] = i3; topk_w[b * 4 + 3] = p3 * inv;
    }
  }
}

// ---------------- per-expert count (no atomics) ----------------
__global__ __launch_bounds__(256) void count_kernel(
    const int* __restrict__ topk_idx, int* __restrict__ counts)
{
  const int e = blockIdx.x;
  int c = 0;
  for (int i = threadIdx.x; i < NPAIR; i += 256) c += (topk_idx[i] == e);
#pragma unroll
  for (int o = 1; o < 64; o <<= 1) c += __shfl_xor(c, o);
  __shared__ int ws[4];
  if ((threadIdx.x & 63) == 0) ws[threadIdx.x >> 6] = c;
  __syncthreads();
  if (threadIdx.x == 0) counts[e] = ws[0] + ws[1] + ws[2] + ws[3];
}

__global__ void offsets_kernel(const int* __restrict__ counts, int* __restrict__ offsets) {
  if (threadIdx.x == 0) {
    int run = 0;
    for (int e = 0; e < NEXP; ++e) { offsets[e] = run; run += counts[e]; }
  }
}

// ---------------- stable scatter (deterministic, no atomics) ----------------
// Emits: token_of_row[pos] (gather for gemm1) and pair_row[t] (inverse, for combine).
__global__ __launch_bounds__(256) void scatter_kernel(
    const int* __restrict__ topk_idx,
    const int* __restrict__ offsets,
    int* __restrict__ token_of_row, int* __restrict__ pair_row)
{
  const int e = blockIdx.x;
  __shared__ int wsum[4];
  __shared__ int chunk_base;
  if (threadIdx.x == 0) chunk_base = offsets[e];
  __syncthreads();
  const int wid = threadIdx.x >> 6, lane = threadIdx.x & 63;
  for (int c0 = 0; c0 < NPAIR; c0 += 256) {
    const int t = c0 + threadIdx.x;
    const bool f = (topk_idx[t] == e);
    const unsigned long long m = __ballot(f);
    const int pre = __popcll(m & ((1ull << lane) - 1ull));
    if (lane == 0) wsum[wid] = __popcll(m);
    __syncthreads();
    int wbase = 0;
#pragma unroll
    for (int i = 0; i < 4; ++i) if (i < wid) wbase += wsum[i];
    const int total = wsum[0] + wsum[1] + wsum[2] + wsum[3];
    if (f) {
      const int pos = chunk_base + wbase + pre;
      token_of_row[pos] = t >> 2;
      pair_row[t] = pos;
    }
    __syncthreads();
    if (threadIdx.x == 0) chunk_base += total;
  }
}

// ---------------- weight transpose+convert: [E][R][C] f32 -> [E][C][R] bf16 ----------------
__global__ __launch_bounds__(256) void transpose_convert_kernel(
    const float* __restrict__ in, __hip_bfloat16* __restrict__ out, int R, int C)
{
  __shared__ float tile[32][33];
  const int e = blockIdx.z;
  const int r0 = blockIdx.y * 32, c0 = blockIdx.x * 32;
  const int x = threadIdx.x & 31, y = threadIdx.x >> 5;   // y: 0..7
  const float* ip = in + ((size_t)e * R + r0) * C + c0;
#pragma unroll
  for (int i = 0; i < 4; ++i) tile[y + 8 * i][x] = ip[(size_t)(y + 8 * i) * C + x];
  __syncthreads();
  __hip_bfloat16* op = out + ((size_t)e * C + c0) * R + r0;
#pragma unroll
  for (int i = 0; i < 4; ++i) op[(size_t)(y + 8 * i) * R + x] = __float2bfloat16(tile[x][y + 8 * i]);
}

// ================= 128x64 grouped GEMM, 4 waves (wave = 64x32), BK=64 =================
// Simple 2-barrier loop; latency hidden by co-resident blocks (24KB LDS -> ~6/CU).
// 1D grid, XCD-chunked swizzle.

// ---------------- GEMM1: a = relu(h @ W1 + b1), gathered rows ----------------
// logical id = e*256 + m*16 + n
__global__ __launch_bounds__(256) void gemm1_kernel(
    const __hip_bfloat16* __restrict__ hb,   // [NTOK, NF]
    const __hip_bfloat16* __restrict__ W1t,  // [E, NH, NF]  (n-major)
    const float* __restrict__ b1,            // [E, NH]
    const int* __restrict__ token_of_row, const int* __restrict__ offsets,
    const int* __restrict__ counts,
    __hip_bfloat16* __restrict__ a_out)      // [NPAIR, NH]
{
  const int bid = blockIdx.x;                      // 4096 blocks
  const int id  = (bid & 7) * 512 + (bid >> 3);    // XCD-chunked
  const int e   = id >> 8;
  const int m0  = ((id >> 4) & 15) * 128;
  const int n0  = (id & 15) * 64;
  const int cnt = counts[e];
  if (m0 >= cnt) return;
  const int off = offsets[e];

  __shared__ __align__(16) __hip_bfloat16 As[8192]; // [g:8][row:128][8]
  __shared__ __align__(16) __hip_bfloat16 Bs[4096]; // [g:8][row:64][8]

  const int tid = threadIdx.x;
  const int w = tid >> 6, l = tid & 63;
  const int wm = w >> 1, wn = w & 1;
  const int r16 = l & 15, g4 = l >> 4;

  int rA0 = off + m0 + l;       if (rA0 > NPAIR - 1) rA0 = NPAIR - 1;
  int rA1 = off + m0 + 64 + l;  if (rA1 > NPAIR - 1) rA1 = NPAIR - 1;
  const __hip_bfloat16* AgL = hb + (size_t)token_of_row[rA0] * NF;
  const __hip_bfloat16* AgH = hb + (size_t)token_of_row[rA1] * NF;
  const __hip_bfloat16* Bg  = W1t + ((size_t)e * NH + n0 + l) * NF;
  const int g0 = 2 * w;
  __hip_bfloat16* AsD = As + g0 * 1024;
  __hip_bfloat16* BsD = Bs + g0 * 512;

  f32x4 acc[4][2] = {};

  for (int k0 = 0; k0 < NF; k0 += 64) {
    __syncthreads();
    gload16_lds(AgL + k0 + g0 * 8,       AsD);
    gload16_lds(AgH + k0 + g0 * 8,       AsD + 512);
    gload16_lds(AgL + k0 + (g0 + 1) * 8, AsD + 1024);
    gload16_lds(AgH + k0 + (g0 + 1) * 8, AsD + 1536);
    gload16_lds(Bg + k0 + g0 * 8,        BsD);
    gload16_lds(Bg + k0 + (g0 + 1) * 8,  BsD + 512);
    __syncthreads();
#pragma unroll
    for (int ks = 0; ks < 2; ++ks) {
      const int g = ks * 4 + g4;
      bf16x8 af[4], bq[2];
#pragma unroll
      for (int rr = 0; rr < 4; ++rr)
        af[rr] = *(const bf16x8*)(As + (g * 128 + wm * 64 + rr * 16 + r16) * 8);
#pragma unroll
      for (int nn = 0; nn < 2; ++nn)
        bq[nn] = *(const bf16x8*)(Bs + (g * 64 + wn * 32 + nn * 16 + r16) * 8);
#pragma unroll
      for (int rr = 0; rr < 4; ++rr)
#pragma unroll
        for (int nn = 0; nn < 2; ++nn)
          acc[rr][nn] = __builtin_amdgcn_mfma_f32_16x16x32_bf16(af[rr], bq[nn], acc[rr][nn], 0, 0, 0);
    }
  }

  const int q4 = l >> 4, cl = l & 15;
  const int mmax = cnt - m0;
#pragma unroll
  for (int rr = 0; rr < 4; ++rr) {
#pragma unroll
    for (int nn = 0; nn < 2; ++nn) {
      const int c = n0 + wn * 32 + nn * 16 + cl;
      const float bias = b1[e * NH + c];
#pragma unroll
      for (int q = 0; q < 4; ++q) {
        const int r = wm * 64 + rr * 16 + q4 * 4 + q;
        if (r < mmax) {
          float v = fmaxf(acc[rr][nn][q] + bias, 0.f);
          a_out[(size_t)(off + m0 + r) * NH + c] = __float2bfloat16(v);
        }
      }
    }
  }
}

// ---------------- GEMM2: ybuf = a @ W2 + b2 (plain f32 stores, NO atomics) ----------------
// logical id = e*128 + m*8 + n   (n: 8 x 64-col, m: 16 x 128-row), K = 1024 full.
__global__ __launch_bounds__(256) void gemm2_kernel(
    const __hip_bfloat16* __restrict__ a_in,  // [NPAIR, NH]
    const __hip_bfloat16* __restrict__ W2t,   // [E, NCOUT, NH] (n-major)
    const float* __restrict__ b2,             // [E, NCOUT]
    const int* __restrict__ offsets, const int* __restrict__ counts,
    float* __restrict__ ybuf)                 // [NPAIR, NCOUT]
{
  const int bid = blockIdx.x;                      // 2048 blocks
  const int id  = (bid & 7) * 256 + (bid >> 3);    // XCD-chunked
  const int e   = id >> 7;
  const int m0  = ((id >> 3) & 15) * 128;
  const int n0  = (id & 7) * 64;
  const int cnt = counts[e];
  if (m0 >= cnt) return;
  const int off = offsets[e];

  __shared__ __align__(16) __hip_bfloat16 As[8192];
  __shared__ __align__(16) __hip_bfloat16 Bs[4096];

  const int tid = threadIdx.x;
  const int w = tid >> 6, l = tid & 63;
  const int wm = w >> 1, wn = w & 1;
  const int r16 = l & 15, g4 = l >> 4;

  int rA0 = off + m0 + l;       if (rA0 > NPAIR - 1) rA0 = NPAIR - 1;
  int rA1 = off + m0 + 64 + l;  if (rA1 > NPAIR - 1) rA1 = NPAIR - 1;
  const __hip_bfloat16* AgL = a_in + (size_t)rA0 * NH;
  const __hip_bfloat16* AgH = a_in + (size_t)rA1 * NH;
  const __hip_bfloat16* Bg  = W2t + ((size_t)e * NCOUT + n0 + l) * NH;
  const int g0 = 2 * w;
  __hip_bfloat16* AsD = As + g0 * 1024;
  __hip_bfloat16* BsD = Bs + g0 * 512;

  f32x4 acc[4][2] = {};

  for (int k0 = 0; k0 < NH; k0 += 64) {
    __syncthreads();
    gload16_lds(AgL + k0 + g0 * 8,       AsD);
    gload16_lds(AgH + k0 + g0 * 8,       AsD + 512);
    gload16_lds(AgL + k0 + (g0 + 1) * 8, AsD + 1024);
    gload16_lds(AgH + k0 + (g0 + 1) * 8, AsD + 1536);
    gload16_lds(Bg + k0 + g0 * 8,        BsD);
    gload16_lds(Bg + k0 + (g0 + 1) * 8,  BsD + 512);
    __syncthreads();
#pragma unroll
    for (int ks = 0; ks < 2; ++ks) {
      const int g = ks * 4 + g4;
      bf16x8 af[4], bq[2];
#pragma unroll
      for (int rr = 0; rr < 4; ++rr)
        af[rr] = *(const bf16x8*)(As + (g * 128 + wm * 64 + rr * 16 + r16) * 8);
#pragma unroll
      for (int nn = 0; nn < 2; ++nn)
        bq[nn] = *(const bf16x8*)(Bs + (g * 64 + wn * 32 + nn * 16 + r16) * 8);
#pragma unroll
      for (int rr = 0; rr < 4; ++rr)
#pragma unroll
        for (int nn = 0; nn < 2; ++nn)
          acc[rr][nn] = __builtin_amdgcn_mfma_f32_16x16x32_bf16(af[rr], bq[nn], acc[rr][nn], 0, 0, 0);
    }
  }

  const int q4 = l >> 4, cl = l & 15;
  const int mmax = cnt - m0;
#pragma unroll
  for (int rr = 0; rr < 4; ++rr) {
#pragma unroll
    for (int nn = 0; nn < 2; ++nn) {
      const int c = n0 + wn * 32 + nn * 16 + cl;
      const float bias = b2[e * NCOUT + c];
#pragma unroll
      for (int q = 0; q < 4; ++q) {
        const int r = wm * 64 + rr * 16 + q4 * 4 + q;
        if (r < mmax)
          ybuf[(size_t)(off + m0 + r) * NCOUT + c] = acc[rr][nn][q] + bias;
      }
    }
  }
}

// ---------------- combine: out[tok] = sum_k w_k * ybuf[pair_row[tok*4+k]] ----------------
__global__ __launch_bounds__(256) void combine_kernel(
    const float* __restrict__ ybuf, const int* __restrict__ pair_row,
    const float* __restrict__ topk_w, float* __restrict__ out)
{
  const int tok = blockIdx.x;
  const int c = threadIdx.x * 2;
  float a0 = 0.f, a1 = 0.f;
#pragma unroll
  for (int k = 0; k < 4; ++k) {
    const int t = tok * 4 + k;
    const float wt = topk_w[t];
    const float2 y = *(const float2*)(ybuf + (size_t)pair_row[t] * NCOUT + c);
    a0 += wt * y.x; a1 += wt * y.y;
  }
  *(float2*)(out + (size_t)tok * NCOUT + c) = make_float2(a0, a1);
}

extern "C" void kernel_launch(void* const* d_in, const int* in_sizes, int n_in,
                              void* d_out, int out_size, void* d_ws, size_t ws_size,
                              hipStream_t stream) {
  (void)in_sizes; (void)n_in; (void)ws_size; (void)out_size;
  const float* h        = (const float*)d_in[0];
  const float* W_mu     = (const float*)d_in[1];
  const float* b_mu     = (const float*)d_in[2];
  const float* W_logvar = (const float*)d_in[3];
  const float* b_logvar = (const float*)d_in[4];
  const float* W1       = (const float*)d_in[5];
  const float* b1       = (const float*)d_in[6];
  const float* W2       = (const float*)d_in[7];
  const float* b2       = (const float*)d_in[8];
  float* out = (float*)d_out;

  char* p = (char*)d_ws;
  int*   counts   = (int*)p;   p += 16 * 4;
  int*   offsets  = (int*)p;   p += 16 * 4;
  float* expb     = (float*)p; p += 16 * 4;
  p += 16 * 4; // pad
  float* expW     = (float*)p; p += (size_t)NEXP * NF * 4;
  int*   topk_idx = (int*)p;   p += (size_t)NPAIR * 4;
  float* topk_w   = (float*)p; p += (size_t)NPAIR * 4;
  int*   tok_row  = (int*)p;   p += (size_t)NPAIR * 4;
  int*   pair_row = (int*)p;   p += (size_t)NPAIR * 4;
  __hip_bfloat16* hb   = (__hip_bfloat16*)p; p += (size_t)NTOK * NF * 2;
  __hip_bfloat16* W1t  = (__hip_bfloat16*)p; p += (size_t)NEXP * NF * NH * 2;
  __hip_bfloat16* W2t  = (__hip_bfloat16*)p; p += (size_t)NEXP * NH * NCOUT * 2;
  __hip_bfloat16* abuf = (__hip_bfloat16*)p; p += (size_t)NPAIR * NH * 2;
  float*          ybuf = (float*)p;          p += (size_t)NPAIR * NCOUT * 4;

  precompute_kernel<<<(NEXP * NF + 255) / 256, 256, 0, stream>>>(W_logvar, b_logvar, expW, expb);
  router_kernel<<<NTOK, 256, 0, stream>>>(h, W_mu, b_mu, expW, expb, topk_idx, topk_w, hb);
  count_kernel<<<NEXP, 256, 0, stream>>>(topk_idx, counts);
  offsets_kernel<<<1, 64, 0, stream>>>(counts, offsets);
  scatter_kernel<<<NEXP, 256, 0, stream>>>(topk_idx, offsets, tok_row, pair_row);

  transpose_convert_kernel<<<dim3(NH / 32, NF / 32, NEXP), 256, 0, stream>>>(W1, W1t, NF, NH);
  transpose_convert_kernel<<<dim3(NCOUT / 32, NH / 32, NEXP), 256, 0, stream>>>(W2, W2t, NH, NCOUT);

  gemm1_kernel<<<4096, 256, 0, stream>>>(hb, W1t, b1, tok_row, offsets, counts, abuf);
  gemm2_kernel<<<2048, 256, 0, stream>>>(abuf, W2t, b2, offsets, counts, ybuf);
  combine_kernel<<<NTOK, 256, 0, stream>>>(ybuf, pair_row, topk_w, out);
}

// Round 7
// 100.111 us; speedup vs baseline: 1.9666x; 1.4759x over previous
//
#include <hip/hip_runtime.h>
#include <hip/hip_bf16.h>

typedef __attribute__((ext_vector_type(8))) short bf16x8;
typedef __attribute__((ext_vector_type(4))) float f32x4;

#define NTOK   2048
#define NEXP   16
#define NF     512
#define NH     1024
#define NCOUT  512
#define NPAIR  8192   // NTOK * 4

__device__ __forceinline__ void gload16_lds(const __hip_bfloat16* g, const __hip_bfloat16* l) {
  __builtin_amdgcn_global_load_lds((const __attribute__((address_space(1))) void*)g,
                                   (__attribute__((address_space(3))) void*)l, 16, 0, 0);
}

// ---------------- precompute exp(W_logvar), exp(b_logvar) ----------------
__global__ __launch_bounds__(256) void precompute_kernel(
    const float* __restrict__ W_logvar, const float* __restrict__ b_logvar,
    float* __restrict__ expW, float* __restrict__ expb)
{
  int i = blockIdx.x * 256 + threadIdx.x;
  if (i < NEXP * NF) expW[i] = expf(W_logvar[i]);
  if (i < NEXP) expb[i] = expf(b_logvar[i]);
}

// ---------------- router: mu/var -> tilde -> top4 + renorm softmax ----------------
__global__ __launch_bounds__(256) void router_kernel(
    const float* __restrict__ h, const float* __restrict__ W_mu,
    const float* __restrict__ b_mu, const float* __restrict__ expW,
    const float* __restrict__ expb,
    int* __restrict__ topk_idx, float* __restrict__ topk_w,
    __hip_bfloat16* __restrict__ hb)
{
  __shared__ __align__(16) float hs[NF], hs2[NF];
  __shared__ float smu[NEXP], svar[NEXP];
  const int b = blockIdx.x, tid = threadIdx.x;
  for (int i = tid; i < NF; i += 256) {
    float v = h[(size_t)b * NF + i];
    hs[i] = v; hs2[i] = v * v;
    hb[(size_t)b * NF + i] = __float2bfloat16(v);
  }
  __syncthreads();
  const int e = tid >> 4, l = tid & 15;
  float mu = 0.f, var = 0.f;
  const float4* wm4 = (const float4*)(W_mu + e * NF);
  const float4* wv4 = (const float4*)(expW + e * NF);
  const float4* h4  = (const float4*)hs;
  const float4* h24 = (const float4*)hs2;
#pragma unroll
  for (int j = 0; j < NF / 64; ++j) {
    int i4 = l + j * 16;
    float4 a = h4[i4],  wa = wm4[i4];
    float4 c = h24[i4], wc = wv4[i4];
    mu  += a.x * wa.x + a.y * wa.y + a.z * wa.z + a.w * wa.w;
    var += c.x * wc.x + c.y * wc.y + c.z * wc.z + c.w * wc.w;
  }
#pragma unroll
  for (int o = 1; o < 16; o <<= 1) { mu += __shfl_xor(mu, o); var += __shfl_xor(var, o); }
  if (l == 0) { smu[e] = mu + b_mu[e]; svar[e] = var + expb[e]; }
  __syncthreads();
  if (tid < 64) {
    float val = -1e30f;
    if (tid < NEXP) {
      float v = fmaxf(svar[tid], 1e-12f);
      val = smu[tid] / sqrtf(1.0f + 0.39269908169872414f * v);  // pi/8
    }
    float mx = 0.f, wsum = 0.f;
    int i0, i1, i2, i3; float p0, p1, p2, p3;
#define TOPK_ROUND(ii, pp, FIRST)                                          \
    {                                                                      \
      float m = val;                                                       \
      m = fmaxf(m, __shfl_xor(m, 1));  m = fmaxf(m, __shfl_xor(m, 2));     \
      m = fmaxf(m, __shfl_xor(m, 4));  m = fmaxf(m, __shfl_xor(m, 8));     \
      m = fmaxf(m, __shfl_xor(m, 16)); m = fmaxf(m, __shfl_xor(m, 32));    \
      unsigned long long bm = __ballot(val == m);                          \
      int bi = (int)__builtin_ctzll(bm);                                   \
      if (FIRST) mx = m;                                                   \
      pp = expf(m - mx); wsum += pp; ii = bi;                              \
      if (tid == bi) val = -1e30f;                                         \
    }
    TOPK_ROUND(i0, p0, 1)
    TOPK_ROUND(i1, p1, 0)
    TOPK_ROUND(i2, p2, 0)
    TOPK_ROUND(i3, p3, 0)
#undef TOPK_ROUND
    if (tid == 0) {
      float inv = 1.0f / fmaxf(wsum, 1e-12f);
      topk_idx[b * 4 + 0] = i0; topk_w[b * 4 + 0] = p0 * inv;
      topk_idx[b * 4 + 1] = i1; topk_w[b * 4 + 1] = p1 * inv;
      topk_idx[b * 4 + 2] = i2; topk_w[b * 4 + 2] = p2 * inv;
      topk_idx[b * 4 + 3] = i3; topk_w[b * 4 + 3] = p3 * inv;
    }
  }
}

// ---------------- per-expert count (no atomics) ----------------
__global__ __launch_bounds__(256) void count_kernel(
    const int* __restrict__ topk_idx, int* __restrict__ counts)
{
  const int e = blockIdx.x;
  int c = 0;
  for (int i = threadIdx.x; i < NPAIR; i += 256) c += (topk_idx[i] == e);
#pragma unroll
  for (int o = 1; o < 64; o <<= 1) c += __shfl_xor(c, o);
  __shared__ int ws[4];
  if ((threadIdx.x & 63) == 0) ws[threadIdx.x >> 6] = c;
  __syncthreads();
  if (threadIdx.x == 0) counts[e] = ws[0] + ws[1] + ws[2] + ws[3];
}

__global__ void offsets_kernel(const int* __restrict__ counts, int* __restrict__ offsets) {
  if (threadIdx.x == 0) {
    int run = 0;
    for (int e = 0; e < NEXP; ++e) { offsets[e] = run; run += counts[e]; }
  }
}

// ---------------- stable scatter (deterministic, no atomics) ----------------
__global__ __launch_bounds__(256) void scatter_kernel(
    const int* __restrict__ topk_idx,
    const int* __restrict__ offsets,
    int* __restrict__ token_of_row, int* __restrict__ pair_row)
{
  const int e = blockIdx.x;
  __shared__ int wsum[4];
  __shared__ int chunk_base;
  if (threadIdx.x == 0) chunk_base = offsets[e];
  __syncthreads();
  const int wid = threadIdx.x >> 6, lane = threadIdx.x & 63;
  for (int c0 = 0; c0 < NPAIR; c0 += 256) {
    const int t = c0 + threadIdx.x;
    const bool f = (topk_idx[t] == e);
    const unsigned long long m = __ballot(f);
    const int pre = __popcll(m & ((1ull << lane) - 1ull));
    if (lane == 0) wsum[wid] = __popcll(m);
    __syncthreads();
    int wbase = 0;
#pragma unroll
    for (int i = 0; i < 4; ++i) if (i < wid) wbase += wsum[i];
    const int total = wsum[0] + wsum[1] + wsum[2] + wsum[3];
    if (f) {
      const int pos = chunk_base + wbase + pre;
      token_of_row[pos] = t >> 2;
      pair_row[t] = pos;
    }
    __syncthreads();
    if (threadIdx.x == 0) chunk_base += total;
  }
}

// ---------------- weight transpose+convert: [E][R][C] f32 -> [E][C][R] bf16 ----------------
__global__ __launch_bounds__(256) void transpose_convert_kernel(
    const float* __restrict__ in, __hip_bfloat16* __restrict__ out, int R, int C)
{
  __shared__ float tile[32][33];
  const int e = blockIdx.z;
  const int r0 = blockIdx.y * 32, c0 = blockIdx.x * 32;
  const int x = threadIdx.x & 31, y = threadIdx.x >> 5;   // y: 0..7
  const float* ip = in + ((size_t)e * R + r0) * C + c0;
#pragma unroll
  for (int i = 0; i < 4; ++i) tile[y + 8 * i][x] = ip[(size_t)(y + 8 * i) * C + x];
  __syncthreads();
  __hip_bfloat16* op = out + ((size_t)e * C + c0) * R + r0;
#pragma unroll
  for (int i = 0; i < 4; ++i) op[(size_t)(y + 8 * i) * R + x] = __float2bfloat16(tile[x][y + 8 * i]);
}

// ================= 128x64 grouped GEMM, coalesced row-major staging =================
// LDS tiles: A [128][64] bf16 (16KB), B [64][64] (8KB), XOR-swizzled k-segments:
//   LDS[row][s] holds global k-segment (s ^ (row&7)), segment = 16B (8 bf16).
// Staging: one gload = 8 rows x 128B contiguous. lane -> row=lane>>3, kseg=lane&7,
//   global kseg loaded = (lane&7) ^ (lane>>3)  (static per lane).
// Frag read: seg = (ks*4+g4) ^ (r16&7)  -> conflict-free (8-way spread, 2-way free).

// ---------------- GEMM1: a = relu(h @ W1 + b1), gathered rows ----------------
// logical id = e*256 + m*16 + n   (m: 16 x 128-row, n: 16 x 64-col)
__global__ __launch_bounds__(256) void gemm1_kernel(
    const __hip_bfloat16* __restrict__ hb,   // [NTOK, NF]
    const __hip_bfloat16* __restrict__ W1t,  // [E, NH, NF]  (n-major)
    const float* __restrict__ b1,            // [E, NH]
    const int* __restrict__ token_of_row, const int* __restrict__ offsets,
    const int* __restrict__ counts,
    __hip_bfloat16* __restrict__ a_out)      // [NPAIR, NH]
{
  const int bid = blockIdx.x;                      // 4096 blocks
  const int id  = (bid & 7) * 512 + (bid >> 3);    // XCD-chunked
  const int e   = id >> 8;
  const int m0  = ((id >> 4) & 15) * 128;
  const int n0  = (id & 15) * 64;
  const int cnt = counts[e];
  if (m0 >= cnt) return;
  const int off = offsets[e];

  __shared__ __align__(16) __hip_bfloat16 As[128 * 64];
  __shared__ __align__(16) __hip_bfloat16 Bs[64 * 64];

  const int tid = threadIdx.x;
  const int w = tid >> 6, l = tid & 63;
  const int wm = w >> 1, wn = w & 1;
  const int r16 = l & 15, g4 = l >> 4;
  const int sx = r16 & 7;
  const int koffL = (((l & 7) ^ (l >> 3)) * 8);    // pre-swizzled k-seg (elems)

  // per-lane A row pointers (4 instr: rows w*32 + i*8 + (l>>3))
  const __hip_bfloat16* Aptr[4];
#pragma unroll
  for (int i = 0; i < 4; ++i) {
    int r = off + m0 + w * 32 + i * 8 + (l >> 3);
    if (r > NPAIR - 1) r = NPAIR - 1;
    Aptr[i] = hb + (size_t)token_of_row[r] * NF + koffL;
  }
  // B rows: w*16 + i*8 + (l>>3)
  const __hip_bfloat16* Bptr[2];
#pragma unroll
  for (int i = 0; i < 2; ++i)
    Bptr[i] = W1t + ((size_t)e * NH + n0 + w * 16 + i * 8 + (l >> 3)) * NF + koffL;

  f32x4 acc[4][2] = {};

  for (int k0 = 0; k0 < NF; k0 += 64) {
    __syncthreads();
#pragma unroll
    for (int i = 0; i < 4; ++i) gload16_lds(Aptr[i] + k0, As + (w * 32 + i * 8) * 64);
#pragma unroll
    for (int i = 0; i < 2; ++i) gload16_lds(Bptr[i] + k0, Bs + (w * 16 + i * 8) * 64);
    __syncthreads();
#pragma unroll
    for (int ks = 0; ks < 2; ++ks) {
      const int seg = (ks * 4 + g4) ^ sx;
      bf16x8 af[4], bq[2];
#pragma unroll
      for (int rr = 0; rr < 4; ++rr)
        af[rr] = *(const bf16x8*)(As + (wm * 64 + rr * 16 + r16) * 64 + seg * 8);
#pragma unroll
      for (int nn = 0; nn < 2; ++nn)
        bq[nn] = *(const bf16x8*)(Bs + (wn * 32 + nn * 16 + r16) * 64 + seg * 8);
#pragma unroll
      for (int rr = 0; rr < 4; ++rr)
#pragma unroll
        for (int nn = 0; nn < 2; ++nn)
          acc[rr][nn] = __builtin_amdgcn_mfma_f32_16x16x32_bf16(af[rr], bq[nn], acc[rr][nn], 0, 0, 0);
    }
  }

  const int q4 = l >> 4, cl = l & 15;
  const int mmax = cnt - m0;
#pragma unroll
  for (int rr = 0; rr < 4; ++rr) {
#pragma unroll
    for (int nn = 0; nn < 2; ++nn) {
      const int c = n0 + wn * 32 + nn * 16 + cl;
      const float bias = b1[e * NH + c];
#pragma unroll
      for (int q = 0; q < 4; ++q) {
        const int r = wm * 64 + rr * 16 + q4 * 4 + q;
        if (r < mmax) {
          float v = fmaxf(acc[rr][nn][q] + bias, 0.f);
          a_out[(size_t)(off + m0 + r) * NH + c] = __float2bfloat16(v);
        }
      }
    }
  }
}

// ---------------- GEMM2: ybuf = a @ W2 + b2 (plain f32 stores) ----------------
// logical id = e*128 + m*8 + n   (m: 16 x 128-row, n: 8 x 64-col), K = 1024.
__global__ __launch_bounds__(256) void gemm2_kernel(
    const __hip_bfloat16* __restrict__ a_in,  // [NPAIR, NH]
    const __hip_bfloat16* __restrict__ W2t,   // [E, NCOUT, NH] (n-major)
    const float* __restrict__ b2,             // [E, NCOUT]
    const int* __restrict__ offsets, const int* __restrict__ counts,
    float* __restrict__ ybuf)                 // [NPAIR, NCOUT]
{
  const int bid = blockIdx.x;                      // 2048 blocks
  const int id  = (bid & 7) * 256 + (bid >> 3);    // XCD-chunked
  const int e   = id >> 7;
  const int m0  = ((id >> 3) & 15) * 128;
  const int n0  = (id & 7) * 64;
  const int cnt = counts[e];
  if (m0 >= cnt) return;
  const int off = offsets[e];

  __shared__ __align__(16) __hip_bfloat16 As[128 * 64];
  __shared__ __align__(16) __hip_bfloat16 Bs[64 * 64];

  const int tid = threadIdx.x;
  const int w = tid >> 6, l = tid & 63;
  const int wm = w >> 1, wn = w & 1;
  const int r16 = l & 15, g4 = l >> 4;
  const int sx = r16 & 7;
  const int koffL = (((l & 7) ^ (l >> 3)) * 8);

  const __hip_bfloat16* Aptr[4];
#pragma unroll
  for (int i = 0; i < 4; ++i) {
    int r = off + m0 + w * 32 + i * 8 + (l >> 3);
    if (r > NPAIR - 1) r = NPAIR - 1;
    Aptr[i] = a_in + (size_t)r * NH + koffL;
  }
  const __hip_bfloat16* Bptr[2];
#pragma unroll
  for (int i = 0; i < 2; ++i)
    Bptr[i] = W2t + ((size_t)e * NCOUT + n0 + w * 16 + i * 8 + (l >> 3)) * NH + koffL;

  f32x4 acc[4][2] = {};

  for (int k0 = 0; k0 < NH; k0 += 64) {
    __syncthreads();
#pragma unroll
    for (int i = 0; i < 4; ++i) gload16_lds(Aptr[i] + k0, As + (w * 32 + i * 8) * 64);
#pragma unroll
    for (int i = 0; i < 2; ++i) gload16_lds(Bptr[i] + k0, Bs + (w * 16 + i * 8) * 64);
    __syncthreads();
#pragma unroll
    for (int ks = 0; ks < 2; ++ks) {
      const int seg = (ks * 4 + g4) ^ sx;
      bf16x8 af[4], bq[2];
#pragma unroll
      for (int rr = 0; rr < 4; ++rr)
        af[rr] = *(const bf16x8*)(As + (wm * 64 + rr * 16 + r16) * 64 + seg * 8);
#pragma unroll
      for (int nn = 0; nn < 2; ++nn)
        bq[nn] = *(const bf16x8*)(Bs + (wn * 32 + nn * 16 + r16) * 64 + seg * 8);
#pragma unroll
      for (int rr = 0; rr < 4; ++rr)
#pragma unroll
        for (int nn = 0; nn < 2; ++nn)
          acc[rr][nn] = __builtin_amdgcn_mfma_f32_16x16x32_bf16(af[rr], bq[nn], acc[rr][nn], 0, 0, 0);
    }
  }

  const int q4 = l >> 4, cl = l & 15;
  const int mmax = cnt - m0;
#pragma unroll
  for (int rr = 0; rr < 4; ++rr) {
#pragma unroll
    for (int nn = 0; nn < 2; ++nn) {
      const int c = n0 + wn * 32 + nn * 16 + cl;
      const float bias = b2[e * NCOUT + c];
#pragma unroll
      for (int q = 0; q < 4; ++q) {
        const int r = wm * 64 + rr * 16 + q4 * 4 + q;
        if (r < mmax)
          ybuf[(size_t)(off + m0 + r) * NCOUT + c] = acc[rr][nn][q] + bias;
      }
    }
  }
}

// ---------------- combine: out[tok] = sum_k w_k * ybuf[pair_row[tok*4+k]] ----------------
__global__ __launch_bounds__(256) void combine_kernel(
    const float* __restrict__ ybuf, const int* __restrict__ pair_row,
    const float* __restrict__ topk_w, float* __restrict__ out)
{
  const int tok = blockIdx.x;
  const int c = threadIdx.x * 2;
  float a0 = 0.f, a1 = 0.f;
#pragma unroll
  for (int k = 0; k < 4; ++k) {
    const int t = tok * 4 + k;
    const float wt = topk_w[t];
    const float2 y = *(const float2*)(ybuf + (size_t)pair_row[t] * NCOUT + c);
    a0 += wt * y.x; a1 += wt * y.y;
  }
  *(float2*)(out + (size_t)tok * NCOUT + c) = make_float2(a0, a1);
}

extern "C" void kernel_launch(void* const* d_in, const int* in_sizes, int n_in,
                              void* d_out, int out_size, void* d_ws, size_t ws_size,
                              hipStream_t stream) {
  (void)in_sizes; (void)n_in; (void)ws_size; (void)out_size;
  const float* h        = (const float*)d_in[0];
  const float* W_mu     = (const float*)d_in[1];
  const float* b_mu     = (const float*)d_in[2];
  const float* W_logvar = (const float*)d_in[3];
  const float* b_logvar = (const float*)d_in[4];
  const float* W1       = (const float*)d_in[5];
  const float* b1       = (const float*)d_in[6];
  const float* W2       = (const float*)d_in[7];
  const float* b2       = (const float*)d_in[8];
  float* out = (float*)d_out;

  char* p = (char*)d_ws;
  int*   counts   = (int*)p;   p += 16 * 4;
  int*   offsets  = (int*)p;   p += 16 * 4;
  float* expb     = (float*)p; p += 16 * 4;
  p += 16 * 4; // pad
  float* expW     = (float*)p; p += (size_t)NEXP * NF * 4;
  int*   topk_idx = (int*)p;   p += (size_t)NPAIR * 4;
  float* topk_w   = (float*)p; p += (size_t)NPAIR * 4;
  int*   tok_row  = (int*)p;   p += (size_t)NPAIR * 4;
  int*   pair_row = (int*)p;   p += (size_t)NPAIR * 4;
  __hip_bfloat16* hb   = (__hip_bfloat16*)p; p += (size_t)NTOK * NF * 2;
  __hip_bfloat16* W1t  = (__hip_bfloat16*)p; p += (size_t)NEXP * NF * NH * 2;
  __hip_bfloat16* W2t  = (__hip_bfloat16*)p; p += (size_t)NEXP * NH * NCOUT * 2;
  __hip_bfloat16* abuf = (__hip_bfloat16*)p; p += (size_t)NPAIR * NH * 2;
  float*          ybuf = (float*)p;          p += (size_t)NPAIR * NCOUT * 4;

  precompute_kernel<<<(NEXP * NF + 255) / 256, 256, 0, stream>>>(W_logvar, b_logvar, expW, expb);
  router_kernel<<<NTOK, 256, 0, stream>>>(h, W_mu, b_mu, expW, expb, topk_idx, topk_w, hb);
  count_kernel<<<NEXP, 256, 0, stream>>>(topk_idx, counts);
  offsets_kernel<<<1, 64, 0, stream>>>(counts, offsets);
  scatter_kernel<<<NEXP, 256, 0, stream>>>(topk_idx, offsets, tok_row, pair_row);

  transpose_convert_kernel<<<dim3(NH / 32, NF / 32, NEXP), 256, 0, stream>>>(W1, W1t, NF, NH);
  transpose_convert_kernel<<<dim3(NCOUT / 32, NH / 32, NEXP), 256, 0, stream>>>(W2, W2t, NH, NCOUT);

  gemm1_kernel<<<4096, 256, 0, stream>>>(hb, W1t, b1, tok_row, offsets, counts, abuf);
  gemm2_kernel<<<2048, 256, 0, stream>>>(abuf, W2t, b2, offsets, counts, ybuf);
  combine_kernel<<<NTOK, 256, 0, stream>>>(ybuf, pair_row, topk_w, out);
}